// Round 2
// baseline (1428.546 us; speedup 1.0000x reference)
//
#include <hip/hip_runtime.h>
#include <hip/hip_bf16.h>

#define N_NODES 50000
#define N_EDGES 800000
#define CH 128
#define ED 64
#define CHUNK 8
#define GPN 4      // nodes per block in k_agg (amortize wcol load)
#define BM 64      // GEMM M-tile
#define BK 32      // GEMM K-chunk
#define LDA (BM + 4)   // 68 floats = 272 B rows (16B-aligned, bank-stride 4)
#define SCAN_BS 512

// ---------------- CSR build ----------------

__global__ void k_hist(const int* __restrict__ dst, int* __restrict__ deg, int E) {
    int e = blockIdx.x * blockDim.x + threadIdx.x;
    if (e < E) atomicAdd(&deg[dst[e]], 1);
}

__global__ void k_scan1(const int* __restrict__ deg, int* __restrict__ blkTot, int n) {
    __shared__ int s[SCAN_BS];
    int tid = threadIdx.x;
    int i = blockIdx.x * SCAN_BS + tid;
    s[tid] = (i < n) ? deg[i] : 0;
    __syncthreads();
    for (int st = SCAN_BS / 2; st > 0; st >>= 1) {
        if (tid < st) s[tid] += s[tid + st];
        __syncthreads();
    }
    if (tid == 0) blkTot[blockIdx.x] = s[0];
}

__global__ void k_scan2(const int* __restrict__ blkTot, int* __restrict__ blkOff, int nblk) {
    __shared__ int s[128];
    int tid = threadIdx.x;
    int v = (tid < nblk) ? blkTot[tid] : 0;
    s[tid] = v;
    __syncthreads();
    for (int st = 1; st < 128; st <<= 1) {
        int t = (tid >= st) ? s[tid - st] : 0;
        __syncthreads();
        s[tid] += t;
        __syncthreads();
    }
    if (tid < nblk) blkOff[tid] = s[tid] - v;  // exclusive
}

__global__ void k_scan3(const int* __restrict__ deg, const int* __restrict__ blkOff,
                        int* __restrict__ offs, int* __restrict__ cursor, int n, int E) {
    __shared__ int s[SCAN_BS];
    int tid = threadIdx.x;
    int i = blockIdx.x * SCAN_BS + tid;
    int v = (i < n) ? deg[i] : 0;
    s[tid] = v;
    __syncthreads();
    for (int st = 1; st < SCAN_BS; st <<= 1) {
        int t = (tid >= st) ? s[tid - st] : 0;
        __syncthreads();
        s[tid] += t;
        __syncthreads();
    }
    int excl = s[tid] - v + blkOff[blockIdx.x];
    if (i < n) { offs[i] = excl; cursor[i] = excl; }
    if (i == 0) offs[n] = E;
}

__global__ void k_scatter(const int* __restrict__ adj, int* __restrict__ cursor,
                          int* __restrict__ slot_src, int* __restrict__ slot_eid, int E) {
    int e = blockIdx.x * blockDim.x + threadIdx.x;
    if (e >= E) return;
    int s = adj[e];
    int d = adj[E + e];
    int pos = atomicAdd(&cursor[d], 1);
    slot_src[pos] = s;
    slot_eid[pos] = e;
}

// ---------------- fused edge-MLP + message + aggregation (node-centric, no atomics) ----------------
// For each node n: z[n] = (1+eps)*x[n] + sum_{e in CSR[n]} relu(x[src_e] + ev[e] @ Wk + eb)
__global__ __launch_bounds__(128) void k_agg(
    const float* __restrict__ x,        // [N][128]
    const float* __restrict__ ev,       // [E][64]
    const int* __restrict__ offs,
    const int* __restrict__ slot_src,
    const int* __restrict__ slot_eid,
    const float* __restrict__ Wk,       // [64][128]
    const float* __restrict__ ebk,      // [128]
    const float* __restrict__ epsk,     // &eps[k]
    float* __restrict__ z)              // [N][128]
{
    const int c = threadIdx.x;          // channel 0..127
    __shared__ float lev[CHUNK][ED];    // staged edge vectors (broadcast reads)

    // W column for this thread's channel: in registers, reused across GPN nodes
    float wcol[ED];
#pragma unroll
    for (int d = 0; d < ED; d++) wcol[d] = Wk[d * CH + c];
    const float ebc = ebk[c];
    const float ep1 = 1.f + *epsk;

    const int jj = c >> 4;              // which edge slot this thread stages
    const int d4 = (c & 15) << 2;       // which 4 floats of the edge vector

    for (int gi = 0; gi < GPN; gi++) {
        const int n = blockIdx.x * GPN + gi;
        if (n >= N_NODES) break;        // uniform per block
        const int beg = offs[n];
        const int end = offs[n + 1];
        float acc = 0.f;
        for (int base = beg; base < end; base += CHUNK) {
            const int m = min(CHUNK, end - base);
            // stage edge vectors for up to CHUNK edges: 16 threads x float4 each
            if (jj < m) {
                const int eid = slot_eid[base + jj];
                *(float4*)(&lev[jj][d4]) = *(const float4*)(ev + (size_t)eid * ED + d4);
            }
            // prefetch x gathers (overlaps with staging latency)
            float xv[CHUNK];
#pragma unroll
            for (int j = 0; j < CHUNK; j++) {
                if (j < m) xv[j] = x[(size_t)slot_src[base + j] * CH + c];
            }
            __syncthreads();
            for (int j = 0; j < m; j++) {
                float a = ebc;
#pragma unroll
                for (int d = 0; d < ED; d++) a = fmaf(lev[j][d], wcol[d], a);
                a += xv[j];
                acc += fmaxf(a, 0.f);
            }
            __syncthreads();
        }
        const float xn = x[(size_t)n * CH + c];
        z[(size_t)n * CH + c] = ep1 * xn + acc;
    }
}

// ---------------- fused MLP: x = relu(LN(relu(BN(z@W1+b1)) @ W2 + b2)) ----------------
// Phase 1: acc = z@W1 -> BN -> ReLU -> HsT (transposed, in LDS; no HBM round-trip of h)
// Phase 2: acc2 = H@W2 (A-fragments straight from HsT) -> +b2 -> LayerNorm -> ReLU -> store
__global__ __launch_bounds__(256) void k_mlp(
    const float* __restrict__ zin,
    const float* __restrict__ W1, const float* __restrict__ b1,
    const float* __restrict__ bng, const float* __restrict__ bnb,
    const float* __restrict__ bnm, const float* __restrict__ bnv,
    const float* __restrict__ W2, const float* __restrict__ b2,
    const float* __restrict__ lng, const float* __restrict__ lnb,
    float* __restrict__ xout)
{
    __shared__ float Bs[BK][CH];        // 16 KB, staged W chunk (both phases)
    __shared__ float HsT[CH][LDA];      // 34.8 KB, transposed hidden tile
    __shared__ float AsRed[BK * LDA];   // 8.7 KB, union: As (phase 1) / red (epilogue 2)

    const int tid = threadIdx.x;
    const int tx = tid & 15, ty = tid >> 4;
    const int c0 = tx * 8, r0 = ty * 4;
    const int rb = blockIdx.x * BM;
    float acc[4][8] = {};

    // ---------- phase 1: acc = z @ W1 ----------
    for (int kb = 0; kb < CH; kb += BK) {
#pragma unroll
        for (int i = 0; i < 2; i++) {   // stage A transposed: 512 float4
            int idx = tid + i * 256;
            int r = idx >> 3, kq = idx & 7;
            int row = rb + r;
            float4 g = make_float4(0.f, 0.f, 0.f, 0.f);
            if (row < N_NODES) g = *(const float4*)(zin + (size_t)row * CH + kb + kq * 4);
            AsRed[(kq * 4 + 0) * LDA + r] = g.x;
            AsRed[(kq * 4 + 1) * LDA + r] = g.y;
            AsRed[(kq * 4 + 2) * LDA + r] = g.z;
            AsRed[(kq * 4 + 3) * LDA + r] = g.w;
        }
#pragma unroll
        for (int i = 0; i < 4; i++) {   // stage B: 1024 float4
            int idx = tid + i * 256;
            int k = idx >> 5, cq = idx & 31;
            *(float4*)(&Bs[k][cq * 4]) = *(const float4*)(W1 + (size_t)(kb + k) * CH + cq * 4);
        }
        __syncthreads();
#pragma unroll
        for (int k = 0; k < BK; k++) {
            float a[4], b[8];
            *(float4*)a = *(const float4*)(&AsRed[k * LDA + r0]);
            *(float4*)b = *(const float4*)(&Bs[k][c0]);
            *(float4*)(b + 4) = *(const float4*)(&Bs[k][c0 + 4]);
#pragma unroll
            for (int i = 0; i < 4; i++)
#pragma unroll
                for (int j = 0; j < 8; j++) acc[i][j] = fmaf(a[i], b[j], acc[i][j]);
        }
        __syncthreads();
    }

    // ---------- epilogue 1: +b1, BatchNorm(eval), ReLU -> HsT ----------
    {
        float sc[8], sh[8], bb[8];
#pragma unroll
        for (int j = 0; j < 8; j++) {
            int cc = c0 + j;
            float s = bng[cc] * rsqrtf(bnv[cc] + 1e-5f);
            sc[j] = s; sh[j] = bnb[cc] - bnm[cc] * s; bb[j] = b1[cc];
        }
#pragma unroll
        for (int i = 0; i < 4; i++)
#pragma unroll
            for (int j = 0; j < 8; j++) {
                float v = (acc[i][j] + bb[j]) * sc[j] + sh[j];
                HsT[c0 + j][r0 + i] = v > 0.f ? v : 0.f;
            }
    }
    __syncthreads();

    // ---------- phase 2: acc2 = H @ W2 (A-frags from HsT) ----------
    float acc2[4][8] = {};
    for (int kb = 0; kb < CH; kb += BK) {
#pragma unroll
        for (int i = 0; i < 4; i++) {
            int idx = tid + i * 256;
            int k = idx >> 5, cq = idx & 31;
            *(float4*)(&Bs[k][cq * 4]) = *(const float4*)(W2 + (size_t)(kb + k) * CH + cq * 4);
        }
        __syncthreads();
#pragma unroll
        for (int k = 0; k < BK; k++) {
            float a[4], b[8];
            *(float4*)a = *(const float4*)(&HsT[kb + k][r0]);
            *(float4*)b = *(const float4*)(&Bs[k][c0]);
            *(float4*)(b + 4) = *(const float4*)(&Bs[k][c0 + 4]);
#pragma unroll
            for (int i = 0; i < 4; i++)
#pragma unroll
                for (int j = 0; j < 8; j++) acc2[i][j] = fmaf(a[i], b[j], acc2[i][j]);
        }
        __syncthreads();
    }

    // ---------- epilogue 2: +b2, LayerNorm(128), ReLU, store ----------
    float bb[8];
#pragma unroll
    for (int j = 0; j < 8; j++) bb[j] = b2[c0 + j];
    float vals[4][8];
#pragma unroll
    for (int i = 0; i < 4; i++) {
        float s1 = 0.f, s2 = 0.f;
#pragma unroll
        for (int j = 0; j < 8; j++) {
            float v = acc2[i][j] + bb[j];
            vals[i][j] = v;
            s1 += v; s2 += v * v;
        }
        AsRed[((r0 + i) * 16 + tx) * 2 + 0] = s1;
        AsRed[((r0 + i) * 16 + tx) * 2 + 1] = s2;
    }
    __syncthreads();
    float g8[8], be8[8];
#pragma unroll
    for (int j = 0; j < 8; j++) { g8[j] = lng[c0 + j]; be8[j] = lnb[c0 + j]; }
#pragma unroll
    for (int i = 0; i < 4; i++) {
        float m1 = 0.f, m2 = 0.f;
        for (int t = 0; t < 16; t++) {
            m1 += AsRed[((r0 + i) * 16 + t) * 2 + 0];
            m2 += AsRed[((r0 + i) * 16 + t) * 2 + 1];
        }
        float mu = m1 * (1.f / 128.f);
        float var = m2 * (1.f / 128.f) - mu * mu;
        float rs = rsqrtf(var + 1e-5f);
        int row = rb + r0 + i;
        if (row < N_NODES) {
            float o[8];
#pragma unroll
            for (int j = 0; j < 8; j++) {
                float v = (vals[i][j] - mu) * rs * g8[j] + be8[j];
                o[j] = v > 0.f ? v : 0.f;
            }
            *(float4*)(xout + (size_t)row * CH + c0) = *(float4*)o;
            *(float4*)(xout + (size_t)row * CH + c0 + 4) = *(float4*)(o + 4);
        }
    }
}

// ---------------- launch ----------------
extern "C" void kernel_launch(void* const* d_in, const int* in_sizes, int n_in,
                              void* d_out, int out_size, void* d_ws, size_t ws_size,
                              hipStream_t stream) {
    const float* fv     = (const float*)d_in[0];
    const int*   adj    = (const int*)d_in[1];
    const float* ev     = (const float*)d_in[2];
    const float* eps    = (const float*)d_in[3];
    const float* edge_W = (const float*)d_in[4];
    const float* edge_b = (const float*)d_in[5];
    const float* W1     = (const float*)d_in[6];
    const float* b1     = (const float*)d_in[7];
    const float* bng    = (const float*)d_in[8];
    const float* bnb    = (const float*)d_in[9];
    const float* bnm    = (const float*)d_in[10];
    const float* bnv    = (const float*)d_in[11];
    const float* W2     = (const float*)d_in[12];
    const float* b2     = (const float*)d_in[13];
    const float* lng    = (const float*)d_in[14];
    const float* lnb    = (const float*)d_in[15];
    float* out = (float*)d_out;

    char* w = (char*)d_ws;
    float* zh = (float*)w;       w += (size_t)N_NODES * CH * sizeof(float);
    float* xA = (float*)w;       w += (size_t)N_NODES * CH * sizeof(float);
    int* deg      = (int*)w;     w += (size_t)N_NODES * sizeof(int);
    int* offs     = (int*)w;     w += (size_t)(N_NODES + 1) * sizeof(int);
    int* cursor   = (int*)w;     w += (size_t)N_NODES * sizeof(int);
    int* blkTot   = (int*)w;     w += 256 * sizeof(int);
    int* blkOff   = (int*)w;     w += 256 * sizeof(int);
    int* slot_src = (int*)w;     w += (size_t)N_EDGES * sizeof(int);
    int* slot_eid = (int*)w;     w += (size_t)N_EDGES * sizeof(int);

    // CSR build (per-call; adj is restored before every timed launch)
    hipMemsetAsync(deg, 0, (size_t)N_NODES * sizeof(int), stream);
    k_hist<<<(N_EDGES + 255) / 256, 256, 0, stream>>>(adj + N_EDGES, deg, N_EDGES);
    int nblk = (N_NODES + SCAN_BS - 1) / SCAN_BS;  // 98
    k_scan1<<<nblk, SCAN_BS, 0, stream>>>(deg, blkTot, N_NODES);
    k_scan2<<<1, 128, 0, stream>>>(blkTot, blkOff, nblk);
    k_scan3<<<nblk, SCAN_BS, 0, stream>>>(deg, blkOff, offs, cursor, N_NODES, N_EDGES);
    k_scatter<<<(N_EDGES + 255) / 256, 256, 0, stream>>>(adj, cursor, slot_src, slot_eid, N_EDGES);

    const float* xin = fv;
    for (int k = 0; k < 3; k++) {
        float* xout = (k == 1) ? xA : out;   // fv -> out -> xA -> out
        k_agg<<<(N_NODES + GPN - 1) / GPN, 128, 0, stream>>>(
            xin, ev, offs, slot_src, slot_eid,
            edge_W + (size_t)k * ED * CH, edge_b + (size_t)k * CH, eps + k, zh);
        k_mlp<<<(N_NODES + BM - 1) / BM, 256, 0, stream>>>(
            zh,
            W1 + (size_t)k * CH * CH, b1 + (size_t)k * CH,
            bng + (size_t)k * CH, bnb + (size_t)k * CH,
            bnm + (size_t)k * CH, bnv + (size_t)k * CH,
            W2 + (size_t)k * CH * CH, b2 + (size_t)k * CH,
            lng, lnb, xout);
        xin = xout;
    }
}